// Round 8
// baseline (337.382 us; speedup 1.0000x reference)
//
#include <hip/hip_runtime.h>
#include <hip/hip_fp16.h>

#define F_IN 128
#define C_DIM 300
#define NEG_SLOPE 0.2f
#define NCT  40           // col-tile count for Bp (640 padded cols)
#define CH   8            // edges per chunk in gat_gather
#define NCONV 320         // convert_w blocks in prep

typedef _Float16 half8 __attribute__((ext_vector_type(8)));
typedef _Float16 half4 __attribute__((ext_vector_type(4)));
typedef _Float16 h2    __attribute__((ext_vector_type(2)));
typedef float    f32x4 __attribute__((ext_vector_type(4)));
typedef float    f32x2 __attribute__((ext_vector_type(2)));

__device__ inline h2 as_h2(unsigned u) { union { unsigned u; h2 h; } c; c.u = u; return c.h; }
__device__ inline unsigned as_u(h2 h)  { union { unsigned u; h2 h; } c; c.h = h; return c.u; }
__device__ inline f32x2 upv(unsigned u) {
    h2 h = as_h2(u);
    f32x2 r; r.x = (float)h.x; r.y = (float)h.y; return r;
}
__device__ inline f32x2 fma2(f32x2 a, f32x2 b, f32x2 c) {
#if __has_builtin(__builtin_elementwise_fma)
    return __builtin_elementwise_fma(a, b, c);
#else
    f32x2 r; r.x = fmaf(a.x, b.x, c.x); r.y = fmaf(a.y, b.y, c.y); return r;
#endif
}

#if __has_builtin(__builtin_amdgcn_fdot2)
__device__ inline float fdot2w(h2 a, h2 b, float c) {
    return __builtin_amdgcn_fdot2(a, b, c, false);
}
#else
__device__ inline float fdot2w(h2 a, h2 b, float c) {
    return fmaf((float)a.y, (float)b.y, fmaf((float)a.x, (float)b.x, c));
}
#endif

// ---------- prep: convert_w (blocks [0,NCONV)) + hist (rest) ----------
// Bp[((ct*4+ks)*64+lane)*8+j] = Wcat[k][nn], nn=ct*16+(lane&15), k=ks*32+(lane>>4)*8+j
__global__ __launch_bounds__(256) void prep(
    const float* __restrict__ Wl, const float* __restrict__ Wr,
    _Float16* __restrict__ Bp, const int* __restrict__ dst,
    unsigned* __restrict__ counts, int nE)
{
    if ((int)blockIdx.x < NCONV) {
        int idx = blockIdx.x * 256 + threadIdx.x;        // 0 .. 640*128-1
        if (idx >= 640 * F_IN) return;
        int nn = idx % 640;                               // coalesced W reads
        int k  = idx / 640;
        float v = 0.f;
        if (nn < 300)                   v = Wl[k * C_DIM + nn];
        else if (nn >= 304 && nn < 604) v = Wr[k * C_DIM + (nn - 304)];
        int ct = nn >> 4, n16 = nn & 15;
        int kr = k & 31,  ks  = k >> 5;
        int lane = ((kr >> 3) << 4) | n16;
        int j = k & 7;
        Bp[((((ct * 4 + ks) * 64) + lane) << 3) | j] = (_Float16)v;
    } else {
        int j = (blockIdx.x - NCONV) * 256 + threadIdx.x;
        if (j < nE) atomicAdd(counts + dst[j], 1u);
    }
}

// ---- 3-phase multi-block exclusive scan (1024 counts per block) ----
__global__ __launch_bounds__(256) void scan_part(
    const unsigned* __restrict__ counts, unsigned* __restrict__ bsum, int n)
{
    __shared__ unsigned s[256];
    const int t = threadIdx.x;
    const int base = blockIdx.x * 1024 + t * 4;
    unsigned v = 0;
    #pragma unroll
    for (int i = 0; i < 4; ++i) {
        int idx = base + i;
        if (idx < n) v += counts[idx];
    }
    s[t] = v;
    __syncthreads();
    for (int off = 128; off > 0; off >>= 1) {
        if (t < off) s[t] += s[t + off];
        __syncthreads();
    }
    if (t == 0) bsum[blockIdx.x] = s[0];
}

__global__ __launch_bounds__(64) void scan_mid(
    unsigned* __restrict__ bsum, unsigned* __restrict__ offs, int nblk, int n)
{
    const int lane = threadIdx.x;
    unsigned v = (lane < nblk) ? bsum[lane] : 0u;
    unsigned inc = v;
    #pragma unroll
    for (int off = 1; off < 64; off <<= 1) {
        unsigned u = __shfl_up(inc, off);
        if (lane >= off) inc += u;
    }
    if (lane < nblk) bsum[lane] = inc - v;
    if (lane == 63) offs[n] = inc;
}

__global__ __launch_bounds__(256) void scan_final(
    const unsigned* __restrict__ counts, const unsigned* __restrict__ bsum,
    unsigned* __restrict__ offs, unsigned* __restrict__ cursor, int n)
{
    __shared__ unsigned s[256];
    const int t = threadIdx.x;
    const int base = blockIdx.x * 1024 + t * 4;
    unsigned c[4];
    unsigned v = 0;
    #pragma unroll
    for (int i = 0; i < 4; ++i) {
        int idx = base + i;
        c[i] = (idx < n) ? counts[idx] : 0u;
        v += c[i];
    }
    s[t] = v;
    __syncthreads();
    for (int off = 1; off < 256; off <<= 1) {
        unsigned u = (t >= off) ? s[t - off] : 0u;
        __syncthreads();
        if (t >= off) s[t] += u;
        __syncthreads();
    }
    unsigned run = bsum[blockIdx.x] + s[t] - v;
    #pragma unroll
    for (int i = 0; i < 4; ++i) {
        int idx = base + i;
        if (idx < n) {
            offs[idx] = run;
            cursor[idx] = run;
            run += c[i];
        }
    }
}

// ---------- scatter_gemm: gemm (blocks [0,ngemm)) + CSR scatter (rest) ----------
// gemm: 128-row blocks, 4 waves, wave owns 32 rows (2 A-tile sets in regs),
// sweeps all 40 col-tiles: per tile 4 b128 B-loads + 8 MFMA.
__global__ __launch_bounds__(256) void scatter_gemm(
    const float* __restrict__ x, const _Float16* __restrict__ Bp,
    const float* __restrict__ bl, const float* __restrict__ br,
    _Float16* __restrict__ xlh, _Float16* __restrict__ xrh, int n,
    const int* __restrict__ src, const int* __restrict__ dst,
    unsigned* __restrict__ cursor, int* __restrict__ csr_src, int nE, int ngemm)
{
    if ((int)blockIdx.x < ngemm) {
        __shared__ __align__(16) _Float16 xs[128][136];   // 34 KB
        const int rb0 = blockIdx.x * 128;
        const int t   = threadIdx.x;

        #pragma unroll
        for (int i = 0; i < 16; ++i) {
            int flat = (i * 256 + t) * 4;                 // 0..16383
            int r = flat >> 7;
            int k = flat & 127;
            int gr = rb0 + r;
            if (gr >= n) gr = n - 1;
            float4 v = *reinterpret_cast<const float4*>(x + (size_t)gr * F_IN + k);
            half4 h = { (_Float16)v.x, (_Float16)v.y, (_Float16)v.z, (_Float16)v.w };
            *reinterpret_cast<half4*>(&xs[r][k]) = h;
        }
        __syncthreads();

        const int w    = t >> 6;
        const int lane = t & 63;
        const int m    = lane & 15;
        const int quad = lane >> 4;

        half8 a0[4], a1[4];
        #pragma unroll
        for (int ks = 0; ks < 4; ++ks) {
            a0[ks] = *reinterpret_cast<const half8*>(&xs[w * 32 + m][ks * 32 + quad * 8]);
            a1[ks] = *reinterpret_cast<const half8*>(&xs[w * 32 + 16 + m][ks * 32 + quad * 8]);
        }
        const int rbase0 = rb0 + w * 32 + quad * 4;

        #pragma unroll 2
        for (int ct = 0; ct < NCT; ++ct) {
            f32x4 acc0 = {0.f, 0.f, 0.f, 0.f};
            f32x4 acc1 = {0.f, 0.f, 0.f, 0.f};
            #pragma unroll
            for (int ks = 0; ks < 4; ++ks) {
                half8 b = *reinterpret_cast<const half8*>(
                    Bp + (((size_t)(ct * 4 + ks) * 64 + lane) << 3));
                acc0 = __builtin_amdgcn_mfma_f32_16x16x32_f16(a0[ks], b, acc0, 0, 0, 0);
                acc1 = __builtin_amdgcn_mfma_f32_16x16x32_f16(a1[ks], b, acc1, 0, 0, 0);
            }
            int col = ct * 16 + m;
            int isL = (col < 300);
            int isR = (col >= 304 && col < 604);
            if (isL | isR) {
                float bv = isL ? bl[col] : br[col - 304];
                _Float16* tab = isL ? (xlh + col) : (xrh + (col - 304));
                #pragma unroll
                for (int reg = 0; reg < 4; ++reg) {
                    int r0 = rbase0 + reg;
                    int r1 = r0 + 16;
                    if (r0 < n) tab[(size_t)r0 * C_DIM] = (_Float16)(acc0[reg] + bv);
                    if (r1 < n) tab[(size_t)r1 * C_DIM] = (_Float16)(acc1[reg] + bv);
                }
            }
        }
    } else {
        int j = (blockIdx.x - ngemm) * 256 + threadIdx.x;
        if (j < nE) {
            unsigned p = atomicAdd(cursor + dst[j], 1u);
            csr_src[p] = src[j];
        }
    }
}

// ---------- gat_gather: fused per-node gather, chunked softmax (8 edges/iter) ----------
__global__ __launch_bounds__(256) void gat_gather(
    const int* __restrict__ csr_src, const unsigned* __restrict__ offs,
    const _Float16* __restrict__ xlh, const _Float16* __restrict__ xrh,
    const float* __restrict__ att, const float* __restrict__ bias,
    const float* __restrict__ lw, const float* __restrict__ lb,
    float* __restrict__ y, int n)
{
    __shared__ __align__(16) float lds[4 * 560];   // per wave: part[8][68]
    float* part = lds + (threadIdx.x >> 6) * 560;

    const int wid  = (blockIdx.x * blockDim.x + threadIdx.x) >> 6;
    const int lane = threadIdx.x & 63;
    if (wid >= n) return;

    const int l2   = 2 * lane;
    const bool has2 = (lane < 22);
    const int t8   = lane & 7;
    const int o    = lane >> 3;
    const int byteoff = lane * 4;

    const _Float16* xrrow = xrh + (size_t)wid * C_DIM;
    h2 xr0 = *(const h2*)(xrrow + l2);
    h2 xr1 = *(const h2*)(xrrow + 128 + l2);
    h2 xr2 = {(_Float16)0, (_Float16)0};
    if (has2) xr2 = *(const h2*)(xrrow + 256 + l2);

    h2 a06[3], a04[3];
    #pragma unroll
    for (int k = 0; k < 3; ++k) {
        int c = 128 * k + l2;
        float ax = (c < C_DIM) ? att[c] : 0.f;
        float ay = (c + 1 < C_DIM) ? att[c + 1] : 0.f;
        a06[k].x = (_Float16)(0.6f * ax); a06[k].y = (_Float16)(0.6f * ay);
        a04[k].x = (_Float16)(0.4f * ax); a04[k].y = (_Float16)(0.4f * ay);
    }

    f32x2 acc2[3] = {{0.f, 0.f}, {0.f, 0.f}, {0.f, 0.f}};
    float den = 0.f;

    const unsigned start = offs[wid];
    const int totalE = (int)(offs[wid + 1] - start) + 1;   // + self loop (k==0)
    const char* basep = (const char*)xlh;

    for (int base = 0; base < totalE; base += CH) {
        int idv = wid;                                      // self-loop & filler
        {
            int k = base + lane;
            if (lane < CH && k > 0 && k < totalE) idv = csr_src[start + k - 1];
        }
        int rowb = idv * (C_DIM * 2);
        int ro[CH];
        #pragma unroll
        for (int tt = 0; tt < CH; ++tt) ro[tt] = __shfl(rowb, tt);

        unsigned pk0[CH], pk1[CH], pk2[CH];
        #pragma unroll
        for (int tt = 0; tt < CH; ++tt) {
            const char* p = basep + ro[tt] + byteoff;
            pk0[tt] = *(const unsigned*)(p);
            pk1[tt] = *(const unsigned*)(p + 256);
            pk2[tt] = 0u;
        }
        if (has2) {
            #pragma unroll
            for (int tt = 0; tt < CH; ++tt)
                pk2[tt] = *(const unsigned*)(basep + ro[tt] + byteoff + 512);
        }

        #pragma unroll
        for (int tt = 0; tt < CH; ++tt) {
            h2 z0 = as_h2(pk0[tt]) + xr0;
            h2 z1 = as_h2(pk1[tt]) + xr1;
            h2 z2 = as_h2(pk2[tt]) + xr2;
            float p = fdot2w(z0, a06[0], 0.f);
            p = fdot2w(as_h2(as_u(z0) & 0x7FFF7FFFu), a04[0], p);
            p = fdot2w(z1, a06[1], p);
            p = fdot2w(as_h2(as_u(z1) & 0x7FFF7FFFu), a04[1], p);
            p = fdot2w(z2, a06[2], p);
            p = fdot2w(as_h2(as_u(z2) & 0x7FFF7FFFu), a04[2], p);
            part[tt * 68 + lane] = p;
        }

        float wgt;
        {
            const int oo = (o + t8) & 7;
            const float* rp = part + t8 * 68 + oo * 8;
            float4 s0 = *(const float4*)(rp + 0);
            float4 s1 = *(const float4*)(rp + 4);
            float e = ((s0.x + s0.y) + (s0.z + s0.w)) + ((s1.x + s1.y) + (s1.z + s1.w));
            e += __shfl_xor(e, 8);
            e += __shfl_xor(e, 16);
            e += __shfl_xor(e, 32);
            bool valid = (base + t8) < totalE;
            wgt = valid ? __expf(fminf(e, 60.f)) : 0.f;
        }

        #pragma unroll
        for (int tt = 0; tt < CH; ++tt) {
            float wt = __shfl(wgt, tt);
            den += wt;
            f32x2 wt2 = {wt, wt};
            acc2[0] = fma2(wt2, upv(pk0[tt]), acc2[0]);
            acc2[1] = fma2(wt2, upv(pk1[tt]), acc2[1]);
            acc2[2] = fma2(wt2, upv(pk2[tt]), acc2[2]);
        }
    }

    const float invd = 1.f / den;
    float dot = 0.f;
    #pragma unroll
    for (int k = 0; k < 3; ++k) {
        #pragma unroll
        for (int j = 0; j < 2; ++j) {
            int c = 128 * k + l2 + j;
            float b = (c < C_DIM) ? bias[c] : 0.f;
            float l = (c < C_DIM) ? lw[c] : 0.f;
            float a = (j == 0) ? acc2[k].x : acc2[k].y;
            float h = fmaf(a, invd, b);
            h = h > 0.f ? h : 0.f;
            dot = fmaf(h, l, dot);
        }
    }
    #pragma unroll
    for (int off = 32; off; off >>= 1) dot += __shfl_xor(dot, off);
    if (lane == 0) y[wid] = 1.f / (1.f + __expf(-(dot + lb[0])));
}

extern "C" void kernel_launch(void* const* d_in, const int* in_sizes, int n_in,
                              void* d_out, int out_size, void* d_ws, size_t ws_size,
                              hipStream_t stream)
{
    const float* x    = (const float*)d_in[0];
    const int*   ei   = (const int*)d_in[1];
    const float* Wl   = (const float*)d_in[2];
    const float* bl   = (const float*)d_in[3];
    const float* Wr   = (const float*)d_in[4];
    const float* br   = (const float*)d_in[5];
    const float* att  = (const float*)d_in[6];
    const float* bias = (const float*)d_in[7];
    const float* lw   = (const float*)d_in[8];
    const float* lb   = (const float*)d_in[9];
    float* y = (float*)d_out;

    const int n  = in_sizes[0] / F_IN;   // 50000
    const int nE = in_sizes[1] / 2;      // 800000
    const int* src_arr = ei;
    const int* dst_arr = ei + nE;
    const int nblk  = (n + 1023) / 1024;   // 49 <= 64
    const int nhist = (nE + 255) / 256;    // 3125
    const int ngemm = (n + 127) / 128;     // 391

    // ws: xlh | xrh | Bp | counts | offs(n+1) | cursor | bsum(64) | csr_src
    _Float16* xlh     = (_Float16*)d_ws;
    _Float16* xrh     = xlh + (size_t)n * C_DIM;
    _Float16* Bp      = xrh + (size_t)n * C_DIM;
    unsigned* counts  = (unsigned*)(Bp + NCT * 4 * 64 * 8);
    unsigned* offs    = counts + n;
    unsigned* cursor  = offs + (n + 1);
    unsigned* bsum    = cursor + n;
    int*      csr_src = (int*)(bsum + 64);

    hipMemsetAsync(counts, 0, (size_t)n * sizeof(unsigned), stream);
    prep<<<NCONV + nhist, 256, 0, stream>>>(Wl, Wr, Bp, dst_arr, counts, nE);
    scan_part<<<nblk, 256, 0, stream>>>(counts, bsum, n);
    scan_mid<<<1, 64, 0, stream>>>(bsum, offs, nblk, n);
    scan_final<<<nblk, 256, 0, stream>>>(counts, bsum, offs, cursor, n);
    scatter_gemm<<<ngemm + nhist, 256, 0, stream>>>(
        x, Bp, bl, br, xlh, xrh, n, src_arr, dst_arr, cursor, csr_src, nE, ngemm);
    gat_gather<<<(n + 3) / 4, 256, 0, stream>>>(csr_src, offs, xlh, xrh, att, bias, lw, lb, y, n);
}

// Round 9
// 328.581 us; speedup vs baseline: 1.0268x; 1.0268x over previous
//
#include <hip/hip_runtime.h>
#include <hip/hip_fp16.h>

#define F_IN 128
#define C_DIM 300
#define NEG_SLOPE 0.2f
#define NCT  40           // col-tile count for Bp (640 padded cols)
#define CH   8            // edges per chunk in gat_gather
#define NCONV 320         // convert_w blocks in prep

typedef _Float16 half8 __attribute__((ext_vector_type(8)));
typedef _Float16 half4 __attribute__((ext_vector_type(4)));
typedef _Float16 h2    __attribute__((ext_vector_type(2)));
typedef float    f32x4 __attribute__((ext_vector_type(4)));
typedef float    f32x2 __attribute__((ext_vector_type(2)));

__device__ inline h2 as_h2(unsigned u) { union { unsigned u; h2 h; } c; c.u = u; return c.h; }
__device__ inline unsigned as_u(h2 h)  { union { unsigned u; h2 h; } c; c.h = h; return c.u; }
__device__ inline f32x2 upv(unsigned u) {
    h2 h = as_h2(u);
    f32x2 r; r.x = (float)h.x; r.y = (float)h.y; return r;
}
__device__ inline f32x2 fma2(f32x2 a, f32x2 b, f32x2 c) {
#if __has_builtin(__builtin_elementwise_fma)
    return __builtin_elementwise_fma(a, b, c);
#else
    f32x2 r; r.x = fmaf(a.x, b.x, c.x); r.y = fmaf(a.y, b.y, c.y); return r;
#endif
}

#if __has_builtin(__builtin_amdgcn_fdot2)
__device__ inline float fdot2w(h2 a, h2 b, float c) {
    return __builtin_amdgcn_fdot2(a, b, c, false);
}
#else
__device__ inline float fdot2w(h2 a, h2 b, float c) {
    return fmaf((float)a.y, (float)b.y, fmaf((float)a.x, (float)b.x, c));
}
#endif

// ---------- prep: convert_w (blocks [0,NCONV)) + hist (rest); no LDS ----------
__global__ __launch_bounds__(256) void prep(
    const float* __restrict__ Wl, const float* __restrict__ Wr,
    _Float16* __restrict__ Bp, const int* __restrict__ dst,
    unsigned* __restrict__ counts, int nE)
{
    if ((int)blockIdx.x < NCONV) {
        int idx = blockIdx.x * 256 + threadIdx.x;        // 0 .. 640*128-1
        if (idx >= 640 * F_IN) return;
        int nn = idx % 640;                               // coalesced W reads
        int k  = idx / 640;
        float v = 0.f;
        if (nn < 300)                   v = Wl[k * C_DIM + nn];
        else if (nn >= 304 && nn < 604) v = Wr[k * C_DIM + (nn - 304)];
        int ct = nn >> 4, n16 = nn & 15;
        int kr = k & 31,  ks  = k >> 5;
        int lane = ((kr >> 3) << 4) | n16;
        int j = k & 7;
        Bp[((((ct * 4 + ks) * 64) + lane) << 3) | j] = (_Float16)v;
    } else {
        int j = (blockIdx.x - NCONV) * 256 + threadIdx.x;
        if (j < nE) atomicAdd(counts + dst[j], 1u);
    }
}

// ---- 3-phase multi-block exclusive scan (1024 counts per block) ----
__global__ __launch_bounds__(256) void scan_part(
    const unsigned* __restrict__ counts, unsigned* __restrict__ bsum, int n)
{
    __shared__ unsigned s[256];
    const int t = threadIdx.x;
    const int base = blockIdx.x * 1024 + t * 4;
    unsigned v = 0;
    #pragma unroll
    for (int i = 0; i < 4; ++i) {
        int idx = base + i;
        if (idx < n) v += counts[idx];
    }
    s[t] = v;
    __syncthreads();
    for (int off = 128; off > 0; off >>= 1) {
        if (t < off) s[t] += s[t + off];
        __syncthreads();
    }
    if (t == 0) bsum[blockIdx.x] = s[0];
}

__global__ __launch_bounds__(64) void scan_mid(
    unsigned* __restrict__ bsum, unsigned* __restrict__ offs, int nblk, int n)
{
    const int lane = threadIdx.x;
    unsigned v = (lane < nblk) ? bsum[lane] : 0u;
    unsigned inc = v;
    #pragma unroll
    for (int off = 1; off < 64; off <<= 1) {
        unsigned u = __shfl_up(inc, off);
        if (lane >= off) inc += u;
    }
    if (lane < nblk) bsum[lane] = inc - v;
    if (lane == 63) offs[n] = inc;
}

__global__ __launch_bounds__(256) void scan_final(
    const unsigned* __restrict__ counts, const unsigned* __restrict__ bsum,
    unsigned* __restrict__ offs, unsigned* __restrict__ cursor, int n)
{
    __shared__ unsigned s[256];
    const int t = threadIdx.x;
    const int base = blockIdx.x * 1024 + t * 4;
    unsigned c[4];
    unsigned v = 0;
    #pragma unroll
    for (int i = 0; i < 4; ++i) {
        int idx = base + i;
        c[i] = (idx < n) ? counts[idx] : 0u;
        v += c[i];
    }
    s[t] = v;
    __syncthreads();
    for (int off = 1; off < 256; off <<= 1) {
        unsigned u = (t >= off) ? s[t - off] : 0u;
        __syncthreads();
        if (t >= off) s[t] += u;
        __syncthreads();
    }
    unsigned run = bsum[blockIdx.x] + s[t] - v;
    #pragma unroll
    for (int i = 0; i < 4; ++i) {
        int idx = base + i;
        if (idx < n) {
            offs[idx] = run;
            cursor[idx] = run;
            run += c[i];
        }
    }
}

// ---------- scatter_csr: standalone, zero LDS, full occupancy ----------
__global__ __launch_bounds__(256) void scatter_csr(
    const int* __restrict__ src, const int* __restrict__ dst,
    unsigned* __restrict__ cursor, int* __restrict__ csr_src, int nE)
{
    int j = blockIdx.x * blockDim.x + threadIdx.x;
    if (j < nE) {
        unsigned p = atomicAdd(cursor + dst[j], 1u);
        csr_src[p] = src[j];
    }
}

// ---------- gemm: 128-row blocks, 4 waves, wave owns 32 rows (2 A-tile sets) ----------
__global__ __launch_bounds__(256) void gemm_xlxr(
    const float* __restrict__ x, const _Float16* __restrict__ Bp,
    const float* __restrict__ bl, const float* __restrict__ br,
    _Float16* __restrict__ xlh, _Float16* __restrict__ xrh, int n)
{
    __shared__ __align__(16) _Float16 xs[128][136];   // 34 KB
    const int rb0 = blockIdx.x * 128;
    const int t   = threadIdx.x;

    #pragma unroll
    for (int i = 0; i < 16; ++i) {
        int flat = (i * 256 + t) * 4;                 // 0..16383
        int r = flat >> 7;
        int k = flat & 127;
        int gr = rb0 + r;
        if (gr >= n) gr = n - 1;
        float4 v = *reinterpret_cast<const float4*>(x + (size_t)gr * F_IN + k);
        half4 h = { (_Float16)v.x, (_Float16)v.y, (_Float16)v.z, (_Float16)v.w };
        *reinterpret_cast<half4*>(&xs[r][k]) = h;
    }
    __syncthreads();

    const int w    = t >> 6;
    const int lane = t & 63;
    const int m    = lane & 15;
    const int quad = lane >> 4;

    half8 a0[4], a1[4];
    #pragma unroll
    for (int ks = 0; ks < 4; ++ks) {
        a0[ks] = *reinterpret_cast<const half8*>(&xs[w * 32 + m][ks * 32 + quad * 8]);
        a1[ks] = *reinterpret_cast<const half8*>(&xs[w * 32 + 16 + m][ks * 32 + quad * 8]);
    }
    const int rbase0 = rb0 + w * 32 + quad * 4;

    #pragma unroll 2
    for (int ct = 0; ct < NCT; ++ct) {
        f32x4 acc0 = {0.f, 0.f, 0.f, 0.f};
        f32x4 acc1 = {0.f, 0.f, 0.f, 0.f};
        #pragma unroll
        for (int ks = 0; ks < 4; ++ks) {
            half8 b = *reinterpret_cast<const half8*>(
                Bp + (((size_t)(ct * 4 + ks) * 64 + lane) << 3));
            acc0 = __builtin_amdgcn_mfma_f32_16x16x32_f16(a0[ks], b, acc0, 0, 0, 0);
            acc1 = __builtin_amdgcn_mfma_f32_16x16x32_f16(a1[ks], b, acc1, 0, 0, 0);
        }
        int col = ct * 16 + m;
        int isL = (col < 300);
        int isR = (col >= 304 && col < 604);
        if (isL | isR) {
            float bv = isL ? bl[col] : br[col - 304];
            _Float16* tab = isL ? (xlh + col) : (xrh + (col - 304));
            #pragma unroll
            for (int reg = 0; reg < 4; ++reg) {
                int r0 = rbase0 + reg;
                int r1 = r0 + 16;
                if (r0 < n) tab[(size_t)r0 * C_DIM] = (_Float16)(acc0[reg] + bv);
                if (r1 < n) tab[(size_t)r1 * C_DIM] = (_Float16)(acc1[reg] + bv);
            }
        }
    }
}

// ---------- gat_gather: fused per-node gather, chunked softmax (8 edges/iter) ----------
__global__ __launch_bounds__(256) void gat_gather(
    const int* __restrict__ csr_src, const unsigned* __restrict__ offs,
    const _Float16* __restrict__ xlh, const _Float16* __restrict__ xrh,
    const float* __restrict__ att, const float* __restrict__ bias,
    const float* __restrict__ lw, const float* __restrict__ lb,
    float* __restrict__ y, int n)
{
    __shared__ __align__(16) float lds[4 * 560];   // per wave: part[8][68]
    float* part = lds + (threadIdx.x >> 6) * 560;

    const int wid  = (blockIdx.x * blockDim.x + threadIdx.x) >> 6;
    const int lane = threadIdx.x & 63;
    if (wid >= n) return;

    const int l2   = 2 * lane;
    const bool has2 = (lane < 22);
    const int t8   = lane & 7;
    const int o    = lane >> 3;
    const int byteoff = lane * 4;

    const _Float16* xrrow = xrh + (size_t)wid * C_DIM;
    h2 xr0 = *(const h2*)(xrrow + l2);
    h2 xr1 = *(const h2*)(xrrow + 128 + l2);
    h2 xr2 = {(_Float16)0, (_Float16)0};
    if (has2) xr2 = *(const h2*)(xrrow + 256 + l2);

    h2 a06[3], a04[3];
    #pragma unroll
    for (int k = 0; k < 3; ++k) {
        int c = 128 * k + l2;
        float ax = (c < C_DIM) ? att[c] : 0.f;
        float ay = (c + 1 < C_DIM) ? att[c + 1] : 0.f;
        a06[k].x = (_Float16)(0.6f * ax); a06[k].y = (_Float16)(0.6f * ay);
        a04[k].x = (_Float16)(0.4f * ax); a04[k].y = (_Float16)(0.4f * ay);
    }

    f32x2 acc2[3] = {{0.f, 0.f}, {0.f, 0.f}, {0.f, 0.f}};
    float den = 0.f;

    const unsigned start = offs[wid];
    const int totalE = (int)(offs[wid + 1] - start) + 1;   // + self loop (k==0)
    const char* basep = (const char*)xlh;

    for (int base = 0; base < totalE; base += CH) {
        int idv = wid;                                      // self-loop & filler
        {
            int k = base + lane;
            if (lane < CH && k > 0 && k < totalE) idv = csr_src[start + k - 1];
        }
        int rowb = idv * (C_DIM * 2);
        int ro[CH];
        #pragma unroll
        for (int tt = 0; tt < CH; ++tt) ro[tt] = __shfl(rowb, tt);

        unsigned pk0[CH], pk1[CH], pk2[CH];
        #pragma unroll
        for (int tt = 0; tt < CH; ++tt) {
            const char* p = basep + ro[tt] + byteoff;
            pk0[tt] = *(const unsigned*)(p);
            pk1[tt] = *(const unsigned*)(p + 256);
            pk2[tt] = 0u;
        }
        if (has2) {
            #pragma unroll
            for (int tt = 0; tt < CH; ++tt)
                pk2[tt] = *(const unsigned*)(basep + ro[tt] + byteoff + 512);
        }

        #pragma unroll
        for (int tt = 0; tt < CH; ++tt) {
            h2 z0 = as_h2(pk0[tt]) + xr0;
            h2 z1 = as_h2(pk1[tt]) + xr1;
            h2 z2 = as_h2(pk2[tt]) + xr2;
            float p = fdot2w(z0, a06[0], 0.f);
            p = fdot2w(as_h2(as_u(z0) & 0x7FFF7FFFu), a04[0], p);
            p = fdot2w(z1, a06[1], p);
            p = fdot2w(as_h2(as_u(z1) & 0x7FFF7FFFu), a04[1], p);
            p = fdot2w(z2, a06[2], p);
            p = fdot2w(as_h2(as_u(z2) & 0x7FFF7FFFu), a04[2], p);
            part[tt * 68 + lane] = p;
        }

        float wgt;
        {
            const int oo = (o + t8) & 7;
            const float* rp = part + t8 * 68 + oo * 8;
            float4 s0 = *(const float4*)(rp + 0);
            float4 s1 = *(const float4*)(rp + 4);
            float e = ((s0.x + s0.y) + (s0.z + s0.w)) + ((s1.x + s1.y) + (s1.z + s1.w));
            e += __shfl_xor(e, 8);
            e += __shfl_xor(e, 16);
            e += __shfl_xor(e, 32);
            bool valid = (base + t8) < totalE;
            wgt = valid ? __expf(fminf(e, 60.f)) : 0.f;
        }

        #pragma unroll
        for (int tt = 0; tt < CH; ++tt) {
            float wt = __shfl(wgt, tt);
            den += wt;
            f32x2 wt2 = {wt, wt};
            acc2[0] = fma2(wt2, upv(pk0[tt]), acc2[0]);
            acc2[1] = fma2(wt2, upv(pk1[tt]), acc2[1]);
            acc2[2] = fma2(wt2, upv(pk2[tt]), acc2[2]);
        }
    }

    const float invd = 1.f / den;
    float dot = 0.f;
    #pragma unroll
    for (int k = 0; k < 3; ++k) {
        #pragma unroll
        for (int j = 0; j < 2; ++j) {
            int c = 128 * k + l2 + j;
            float b = (c < C_DIM) ? bias[c] : 0.f;
            float l = (c < C_DIM) ? lw[c] : 0.f;
            float a = (j == 0) ? acc2[k].x : acc2[k].y;
            float h = fmaf(a, invd, b);
            h = h > 0.f ? h : 0.f;
            dot = fmaf(h, l, dot);
        }
    }
    #pragma unroll
    for (int off = 32; off; off >>= 1) dot += __shfl_xor(dot, off);
    if (lane == 0) y[wid] = 1.f / (1.f + __expf(-(dot + lb[0])));
}

extern "C" void kernel_launch(void* const* d_in, const int* in_sizes, int n_in,
                              void* d_out, int out_size, void* d_ws, size_t ws_size,
                              hipStream_t stream)
{
    const float* x    = (const float*)d_in[0];
    const int*   ei   = (const int*)d_in[1];
    const float* Wl   = (const float*)d_in[2];
    const float* bl   = (const float*)d_in[3];
    const float* Wr   = (const float*)d_in[4];
    const float* br   = (const float*)d_in[5];
    const float* att  = (const float*)d_in[6];
    const float* bias = (const float*)d_in[7];
    const float* lw   = (const float*)d_in[8];
    const float* lb   = (const float*)d_in[9];
    float* y = (float*)d_out;

    const int n  = in_sizes[0] / F_IN;   // 50000
    const int nE = in_sizes[1] / 2;      // 800000
    const int* src_arr = ei;
    const int* dst_arr = ei + nE;
    const int nblk  = (n + 1023) / 1024;   // 49 <= 64
    const int nhist = (nE + 255) / 256;    // 3125
    const int ngemm = (n + 127) / 128;     // 391

    // ws: xlh | xrh | Bp | counts | offs(n+1) | cursor | bsum(64) | csr_src
    _Float16* xlh     = (_Float16*)d_ws;
    _Float16* xrh     = xlh + (size_t)n * C_DIM;
    _Float16* Bp      = xrh + (size_t)n * C_DIM;
    unsigned* counts  = (unsigned*)(Bp + NCT * 4 * 64 * 8);
    unsigned* offs    = counts + n;
    unsigned* cursor  = offs + (n + 1);
    unsigned* bsum    = cursor + n;
    int*      csr_src = (int*)(bsum + 64);

    hipMemsetAsync(counts, 0, (size_t)n * sizeof(unsigned), stream);
    prep<<<NCONV + nhist, 256, 0, stream>>>(Wl, Wr, Bp, dst_arr, counts, nE);
    scan_part<<<nblk, 256, 0, stream>>>(counts, bsum, n);
    scan_mid<<<1, 64, 0, stream>>>(bsum, offs, nblk, n);
    scan_final<<<nblk, 256, 0, stream>>>(counts, bsum, offs, cursor, n);
    scatter_csr<<<nhist, 256, 0, stream>>>(src_arr, dst_arr, cursor, csr_src, nE);
    gemm_xlxr<<<ngemm, 256, 0, stream>>>(x, Bp, bl, br, xlh, xrh, n);
    gat_gather<<<(n + 3) / 4, 256, 0, stream>>>(csr_src, offs, xlh, xrh, att, bias, lw, lb, y, n);
}